// Round 1
// 741.538 us; speedup vs baseline: 1.0429x; 1.0429x over previous
//
#include <hip/hip_runtime.h>
#include <hip/hip_bf16.h>

#define T_TOK 4096
#define H_DIM 2048
#define E_NUM 8
#define I_DIM 1408
#define RTOT  8192
#define MAXMT 40           // max padded 256-row m-tiles (8192/256 + 8 = 40)
#define NT1   11           // gemm1 n-tiles (2816/256)
#define NKT1  64           // gemm1 k-tiles (2048/32)
#define NT2   8            // gemm2 n-tiles (2048/256)
#define NKT2  44           // gemm2 k-tiles (1408/32)

// LDS geometry in ushorts: unit = 8 ushorts (16B); q-block = 256 units + 32-ushort (64B) pad
#define QBLK  2080         // 256*8 + 32
#define AREG  8320         // 4*QBLK (A region size per buffer)
#define BUFU  16640        // 2*AREG (A+B) per buffer
#define LDSZ  (4 * BUFU * 2)  // 133120 bytes, 4-deep ring

typedef __bf16 bf16x8 __attribute__((ext_vector_type(8)));
typedef float  floatx4 __attribute__((ext_vector_type(4)));
typedef unsigned short ushortx8 __attribute__((ext_vector_type(8)));

#define VMCNT(n) asm volatile("s_waitcnt vmcnt(" #n ")" ::: "memory")

__device__ __forceinline__ unsigned short f2bf(float f) {
  union { float f; unsigned u; } v; v.f = f;
  unsigned r = v.u + 0x7FFFu + ((v.u >> 16) & 1u);  // RNE
  return (unsigned short)(r >> 16);
}

__device__ __forceinline__ void async16(const void* g, void* l) {
  __builtin_amdgcn_global_load_lds(
      (__attribute__((address_space(1))) void*)(g),
      (__attribute__((address_space(3))) void*)(l), 16, 0, 0);
}

// ---------------- router ----------------
__global__ void router_kernel(const float* __restrict__ x, const float* __restrict__ rw,
                              int* __restrict__ topk_idx, float* __restrict__ topk_w,
                              int* __restrict__ counts) {
  int wave = threadIdx.x >> 6, lane = threadIdx.x & 63;
  int t = blockIdx.x * 4 + wave;
  const float* xr = x + (size_t)t * H_DIM;
  float acc[E_NUM];
#pragma unroll
  for (int e = 0; e < E_NUM; e++) acc[e] = 0.f;
  for (int h = lane; h < H_DIM; h += 64) {
    float xv = xr[h];
    const float* wr = rw + h * E_NUM;
#pragma unroll
    for (int e = 0; e < E_NUM; e++) acc[e] += xv * wr[e];
  }
#pragma unroll
  for (int e = 0; e < E_NUM; e++) {
    float v = acc[e];
#pragma unroll
    for (int s = 32; s > 0; s >>= 1) v += __shfl_xor(v, s, 64);
    acc[e] = v;
  }
  if (lane == 0) {
    float mx = acc[0];
#pragma unroll
    for (int e = 1; e < E_NUM; e++) mx = fmaxf(mx, acc[e]);
    float p[E_NUM], s = 0.f;
#pragma unroll
    for (int e = 0; e < E_NUM; e++) { p[e] = __expf(acc[e] - mx); s += p[e]; }
    float inv = 1.0f / s;
    int i0 = 0;
#pragma unroll
    for (int e = 1; e < E_NUM; e++) if (p[e] > p[i0]) i0 = e;
    int i1 = (i0 == 0) ? 1 : 0;
#pragma unroll
    for (int e = 0; e < E_NUM; e++) if (e != i0 && p[e] > p[i1]) i1 = e;
    topk_idx[t * 2]     = i0;
    topk_idx[t * 2 + 1] = i1;
    topk_w[t * 2]       = p[i0] * inv;
    topk_w[t * 2 + 1]   = p[i1] * inv;
    atomicAdd(&counts[i0], 1);
    atomicAdd(&counts[i1], 1);
  }
}

// scan: 256-padded expert offsets + exact 256-row m-tile table
__global__ void scan_kernel(const int* __restrict__ counts, int* __restrict__ cursors,
                            int* __restrict__ tile_e, int* __restrict__ tile_end) {
  if (threadIdx.x == 0) {
    int o = 0, nt = 0;
    for (int e = 0; e < E_NUM; e++) {
      cursors[e] = o;
      int c = counts[e];
      int ntile = (c + 255) >> 8;
      for (int j = 0; j < ntile; j++) { tile_e[nt] = e; tile_end[nt] = o + c; nt++; }
      o += ntile << 8;
    }
    for (; nt < MAXMT; nt++) { tile_e[nt] = -1; tile_end[nt] = 0; }
  }
}

__global__ void assign_kernel(const int* __restrict__ topk_idx, int* __restrict__ cursors,
                              int* __restrict__ row_of, int* __restrict__ tok_of) {
  int i = blockIdx.x * blockDim.x + threadIdx.x;
  int e = topk_idx[i];
  int row = atomicAdd(&cursors[e], 1);
  row_of[i] = row;
  tok_of[row] = i >> 1;
}

// ---------------- gather: x -> Xp tiled [mt][kt][q][r][8] bf16 ----------------
__global__ void gather_kernel(const float* __restrict__ x, const int* __restrict__ tok_of,
                              const int* __restrict__ tile_e, const int* __restrict__ tile_end,
                              unsigned short* __restrict__ Xp) {
  int kt = blockIdx.x;   // 0..63
  int mt = blockIdx.y;   // 0..39
  if (tile_e[mt] < 0) return;
  int r = threadIdx.x;
  int row = mt * 256 + r;
  int end = tile_end[mt];
  int rr = row < end ? row : end - 1;   // clamp pad rows to a valid token (junk ok, masked later)
  int tok = tok_of[rr];
  const float4* xr = (const float4*)(x + (size_t)tok * H_DIM + kt * 32);
  float v[32];
#pragma unroll
  for (int p = 0; p < 8; p++) {
    float4 t4 = xr[p];
    v[p * 4 + 0] = t4.x; v[p * 4 + 1] = t4.y; v[p * 4 + 2] = t4.z; v[p * 4 + 3] = t4.w;
  }
  unsigned short* dst = Xp + ((size_t)mt * NKT1 + kt) * 8192;
#pragma unroll
  for (int q = 0; q < 4; q++) {
    ushortx8 o;
#pragma unroll
    for (int j = 0; j < 8; j++) o[j] = f2bf(v[q * 8 + j]);
    *(ushortx8*)(dst + ((size_t)q * 256 + r) * 8) = o;
  }
}

// ---- convert gate_up (E,H,2I) fp32 -> W1T tiled [e][nt][kt][q][r][8] bf16,
//      with gate/up column-interleaved at 16-col granularity (even 16-block = gate, odd = up)
__global__ void convert_gu_kernel(const float* __restrict__ W, unsigned short* __restrict__ W1T) {
  int kt = blockIdx.x;   // 0..63 over H
  int nt = blockIdx.y;   // 0..10 over 2816 phys cols
  int e  = blockIdx.z;
  int r  = threadIdx.x;  // 0..255
  int n_phys = nt * 256 + r;
  int b = n_phys >> 4;
  int src_col = ((b >> 1) << 4) + (n_phys & 15) + ((b & 1) ? I_DIM : 0);
  const float* src = W + ((size_t)e * H_DIM + (size_t)kt * 32) * (2 * I_DIM) + src_col;
  float v[32];
#pragma unroll
  for (int k = 0; k < 32; k++) v[k] = src[(size_t)k * (2 * I_DIM)];
  unsigned short* dst = W1T + ((size_t)(e * NT1 + nt) * NKT1 + kt) * 8192;
#pragma unroll
  for (int q = 0; q < 4; q++) {
    ushortx8 o;
#pragma unroll
    for (int j = 0; j < 8; j++) o[j] = f2bf(v[q * 8 + j]);
    *(ushortx8*)(dst + ((size_t)q * 256 + r) * 8) = o;
  }
}

// ---- convert down (E,I,H) fp32 -> WdT tiled [e][nt][kt][q][r][8] bf16 (n over H, k over I)
__global__ void convert_dn_kernel(const float* __restrict__ W, unsigned short* __restrict__ WdT) {
  int kt = blockIdx.x;   // 0..43 over I
  int nt = blockIdx.y;   // 0..7 over H
  int e  = blockIdx.z;
  int r  = threadIdx.x;
  int src_col = nt * 256 + r;
  const float* src = W + (size_t)e * I_DIM * H_DIM + (size_t)kt * 32 * H_DIM + src_col;
  float v[32];
#pragma unroll
  for (int k = 0; k < 32; k++) v[k] = src[(size_t)k * H_DIM];
  unsigned short* dst = WdT + ((size_t)(e * NT2 + nt) * NKT2 + kt) * 8192;
#pragma unroll
  for (int q = 0; q < 4; q++) {
    ushortx8 o;
#pragma unroll
    for (int j = 0; j < 8; j++) o[j] = f2bf(v[q * 8 + j]);
    *(ushortx8*)(dst + ((size_t)q * 256 + r) * 8) = o;
  }
}

// ---------------- GEMM1: 256x256 tile, BK=32, 8 waves, 4-deep ring, counted vmcnt ----------------
__global__ __launch_bounds__(512, 2) void gemm1_kernel(
    const unsigned short* __restrict__ Xp, const unsigned short* __restrict__ W1T,
    const int* __restrict__ tile_e, const int* __restrict__ tile_end,
    unsigned short* __restrict__ Hmid) {
  extern __shared__ unsigned short sm[];
  int bid = blockIdx.x;
  int mt = bid % MAXMT, nt = bid / MAXMT;
  int e = tile_e[mt];
  if (e < 0) return;
  int row_end = tile_end[mt];
  int tid = threadIdx.x, wave = tid >> 6, lane = tid & 63;
  int wm = wave >> 2, wn = wave & 3;
  int q = lane >> 4, l15 = lane & 15;

  const unsigned short* gA = Xp  + (size_t)mt * ((size_t)NKT1 * 8192) + tid * 8;
  const unsigned short* gB = W1T + (size_t)(e * NT1 + nt) * ((size_t)NKT1 * 8192) + tid * 8;

  const int u1 = tid + 512;
  const int dA0 = tid * 8 + (tid >> 8) * 32;
  const int dA1 = u1 * 8 + (u1 >> 8) * 32;

  auto STAGE = [&](int buf) {
    unsigned short* sb = sm + buf * BUFU;
    async16(gA,        sb + dA0);
    async16(gA + 4096, sb + dA1);
    async16(gB,        sb + AREG + dA0);
    async16(gB + 4096, sb + AREG + dA1);
    gA += 8192; gB += 8192;
  };

  STAGE(0); STAGE(1);

  const int off_a = q * QBLK + (wm * 128 + l15) * 8;
  const int off_b = AREG + q * QBLK + (wn * 64 + l15) * 8;

  floatx4 acc[8][4] = {};

  for (int t = 0; t < NKT1; t++) {
    if (t + 1 < NKT1) { VMCNT(4); } else { VMCNT(0); }
    __builtin_amdgcn_s_barrier();
    __builtin_amdgcn_sched_barrier(0);
    if (t + 2 < NKT1) STAGE((t + 2) & 3);
    const unsigned short* base = sm + (t & 3) * BUFU;
    bf16x8 a[8], b[4];
#pragma unroll
    for (int mi = 0; mi < 8; mi++) a[mi] = *(const bf16x8*)(base + off_a + mi * 128);
#pragma unroll
    for (int ni = 0; ni < 4; ni++) b[ni] = *(const bf16x8*)(base + off_b + ni * 128);
    __builtin_amdgcn_s_setprio(1);
#pragma unroll
    for (int ni = 0; ni < 4; ni++)
#pragma unroll
      for (int mi = 0; mi < 8; mi++)
        acc[mi][ni] = __builtin_amdgcn_mfma_f32_16x16x32_bf16(a[mi], b[ni], acc[mi][ni], 0, 0, 0);
    __builtin_amdgcn_s_setprio(0);
  }

  // epilogue: silu(gate)*up from (even,odd) n-frag pairs -> Hmid tiled for gemm2
  const int rt_base = wm * 128 + (lane >> 4) * 4;
  const int lc0 = nt * 128 + wn * 32 + l15;
  unsigned short* Hb = Hmid + (size_t)mt * ((size_t)NKT2 * 8192);
  int rend = row_end - mt * 256;
#pragma unroll
  for (int mi = 0; mi < 8; mi++) {
#pragma unroll
    for (int p = 0; p < 2; p++) {
      int lcol = lc0 + p * 16;
      int kt2 = lcol >> 5, q2 = (lcol >> 3) & 3, j2 = lcol & 7;
      unsigned short* hp = Hb + (size_t)kt2 * 8192 + q2 * 2048 + j2;
#pragma unroll
      for (int r = 0; r < 4; r++) {
        int rt = rt_base + mi * 16 + r;
        if (rt < rend) {
          float g = acc[mi][2 * p][r];
          float u = acc[mi][2 * p + 1][r];
          float s = g / (1.0f + __expf(-g));
          hp[rt * 8] = f2bf(s * u);
        }
      }
    }
  }
}

// ---------------- GEMM2: Hmid(tiled) @ WdT -> H2 fp32 ----------------
__global__ __launch_bounds__(512, 2) void gemm2_kernel(
    const unsigned short* __restrict__ Hmid, const unsigned short* __restrict__ WdT,
    const int* __restrict__ tile_e, const int* __restrict__ tile_end,
    float* __restrict__ H2) {
  extern __shared__ unsigned short sm[];
  int bid = blockIdx.x;
  int mt = bid % MAXMT, nt = bid / MAXMT;
  int e = tile_e[mt];
  if (e < 0) return;
  int row_end = tile_end[mt];
  int tid = threadIdx.x, wave = tid >> 6, lane = tid & 63;
  int wm = wave >> 2, wn = wave & 3;
  int q = lane >> 4, l15 = lane & 15;

  const unsigned short* gA = Hmid + (size_t)mt * ((size_t)NKT2 * 8192) + tid * 8;
  const unsigned short* gB = WdT  + (size_t)(e * NT2 + nt) * ((size_t)NKT2 * 8192) + tid * 8;

  const int u1 = tid + 512;
  const int dA0 = tid * 8 + (tid >> 8) * 32;
  const int dA1 = u1 * 8 + (u1 >> 8) * 32;

  auto STAGE = [&](int buf) {
    unsigned short* sb = sm + buf * BUFU;
    async16(gA,        sb + dA0);
    async16(gA + 4096, sb + dA1);
    async16(gB,        sb + AREG + dA0);
    async16(gB + 4096, sb + AREG + dA1);
    gA += 8192; gB += 8192;
  };

  STAGE(0); STAGE(1);

  const int off_a = q * QBLK + (wm * 128 + l15) * 8;
  const int off_b = AREG + q * QBLK + (wn * 64 + l15) * 8;

  floatx4 acc[8][4] = {};

  for (int t = 0; t < NKT2; t++) {
    if (t + 1 < NKT2) { VMCNT(4); } else { VMCNT(0); }
    __builtin_amdgcn_s_barrier();
    __builtin_amdgcn_sched_barrier(0);
    if (t + 2 < NKT2) STAGE(((unsigned)(t + 2)) & 3);
    const unsigned short* base = sm + (t & 3) * BUFU;
    bf16x8 a[8], b[4];
#pragma unroll
    for (int mi = 0; mi < 8; mi++) a[mi] = *(const bf16x8*)(base + off_a + mi * 128);
#pragma unroll
    for (int ni = 0; ni < 4; ni++) b[ni] = *(const bf16x8*)(base + off_b + ni * 128);
    __builtin_amdgcn_s_setprio(1);
#pragma unroll
    for (int ni = 0; ni < 4; ni++)
#pragma unroll
      for (int mi = 0; mi < 8; mi++)
        acc[mi][ni] = __builtin_amdgcn_mfma_f32_16x16x32_bf16(a[mi], b[ni], acc[mi][ni], 0, 0, 0);
    __builtin_amdgcn_s_setprio(0);
  }

  const int rt_base = wm * 128 + (lane >> 4) * 4;
  const int nb = nt * 256 + wn * 64 + l15;
  float* H2b = H2 + (size_t)mt * 256 * H_DIM + nb;
  int rend = row_end - mt * 256;
#pragma unroll
  for (int mi = 0; mi < 8; mi++) {
#pragma unroll
    for (int ni = 0; ni < 4; ni++) {
#pragma unroll
      for (int r = 0; r < 4; r++) {
        int rt = rt_base + mi * 16 + r;
        if (rt < rend) H2b[(size_t)rt * H_DIM + ni * 16] = acc[mi][ni][r];
      }
    }
  }
}

// ---------------- combine: out[t] = w0*H2[r0] + w1*H2[r1] ----------------
__global__ void combine_kernel(const float* __restrict__ H2, const int* __restrict__ row_of,
                               const float* __restrict__ topk_w, float* __restrict__ out) {
  int t = blockIdx.x >> 1;
  int part = blockIdx.x & 1;
  int c = part * 1024 + threadIdx.x * 4;
  int r0 = row_of[t * 2], r1 = row_of[t * 2 + 1];
  float w0 = topk_w[t * 2], w1 = topk_w[t * 2 + 1];
  float4 a = *(const float4*)(H2 + (size_t)r0 * H_DIM + c);
  float4 b = *(const float4*)(H2 + (size_t)r1 * H_DIM + c);
  float4 o;
  o.x = w0 * a.x + w1 * b.x;
  o.y = w0 * a.y + w1 * b.y;
  o.z = w0 * a.z + w1 * b.z;
  o.w = w0 * a.w + w1 * b.w;
  *(float4*)(out + (size_t)t * H_DIM + c) = o;
}

extern "C" void kernel_launch(void* const* d_in, const int* in_sizes, int n_in,
                              void* d_out, int out_size, void* d_ws, size_t ws_size,
                              hipStream_t stream) {
  const float* x   = (const float*)d_in[0];
  const float* rw  = (const float*)d_in[1];
  const float* wgu = (const float*)d_in[2];
  const float* wdn = (const float*)d_in[3];
  float* out = (float*)d_out;

  static bool attr_done = false;
  if (!attr_done) {
    hipFuncSetAttribute(reinterpret_cast<const void*>(gemm1_kernel),
                        hipFuncAttributeMaxDynamicSharedMemorySize, LDSZ);
    hipFuncSetAttribute(reinterpret_cast<const void*>(gemm2_kernel),
                        hipFuncAttributeMaxDynamicSharedMemorySize, LDSZ);
    attr_done = true;
  }

  char* ws = (char*)d_ws;
  size_t off = 0;
  auto alloc = [&](size_t b) {
    char* p = ws + off;
    off = (off + b + 255) & ~(size_t)255;
    return p;
  };
  unsigned short* W1T  = (unsigned short*)alloc((size_t)E_NUM * NT1 * NKT1 * 8192 * 2);
  unsigned short* WdT  = (unsigned short*)alloc((size_t)E_NUM * NT2 * NKT2 * 8192 * 2);
  unsigned short* Xp   = (unsigned short*)alloc((size_t)MAXMT * NKT1 * 8192 * 2);
  unsigned short* Hmid = (unsigned short*)alloc((size_t)MAXMT * NKT2 * 8192 * 2);
  float* H2            = (float*)alloc((size_t)MAXMT * 256 * H_DIM * 4);
  int*   topk_idx      = (int*)alloc(RTOT * 4);
  float* topk_w        = (float*)alloc(RTOT * 4);
  int*   row_of        = (int*)alloc(RTOT * 4);
  int*   tok_of        = (int*)alloc((size_t)MAXMT * 256 * 4);
  int*   counts        = (int*)alloc(256);
  int*   cursors       = (int*)alloc(256);
  int*   tile_e        = (int*)alloc(64 * 4);
  int*   tile_end      = (int*)alloc(64 * 4);

  hipMemsetAsync(counts, 0, E_NUM * sizeof(int), stream);

  convert_gu_kernel<<<dim3(NKT1, NT1, E_NUM), 256, 0, stream>>>(wgu, W1T);
  convert_dn_kernel<<<dim3(NKT2, NT2, E_NUM), 256, 0, stream>>>(wdn, WdT);
  router_kernel<<<T_TOK / 4, 256, 0, stream>>>(x, rw, topk_idx, topk_w, counts);
  scan_kernel<<<1, 64, 0, stream>>>(counts, cursors, tile_e, tile_end);
  assign_kernel<<<RTOT / 256, 256, 0, stream>>>(topk_idx, cursors, row_of, tok_of);
  gather_kernel<<<dim3(NKT1, MAXMT), 256, 0, stream>>>(x, tok_of, tile_e, tile_end, Xp);
  gemm1_kernel<<<MAXMT * NT1, 512, LDSZ, stream>>>(Xp, W1T, tile_e, tile_end, Hmid);
  gemm2_kernel<<<MAXMT * NT2, 512, LDSZ, stream>>>(Hmid, WdT, tile_e, tile_end, H2);
  combine_kernel<<<T_TOK * 2, 256, 0, stream>>>(H2, row_of, topk_w, out);
}

// Round 3
// 709.275 us; speedup vs baseline: 1.0903x; 1.0455x over previous
//
#include <hip/hip_runtime.h>
#include <hip/hip_bf16.h>

#define T_TOK 4096
#define H_DIM 2048
#define E_NUM 8
#define I_DIM 1408
#define RTOT  8192
#define N1DIM 2816          // gemm1 N (gate|up interleaved)
#define MAXMT 40
#define MAXROWS 10752
#define NT1   11
#define NKT1  64
#define NKT2  44
#define G1_BLOCKS 440       // 8 xcd * 5 mt * 11 nt
#define DN_BLOCKS 1408      // 8 e * 4 nb * 44 kt
#define GU_BLOCKS 5632      // 8 e * 11 ntb * 64 kt
#define RT_BLOCKS 1024

// both GEMMs: ring4 x (A 16KB + B 16KB) = 128 KB  (proven footprint)
#define BUF1U 16384         // ushorts per ring slot
#define LDS1  131072

typedef __bf16 bf16x8 __attribute__((ext_vector_type(8)));
typedef float  floatx4 __attribute__((ext_vector_type(4)));
typedef unsigned short ushortx8 __attribute__((ext_vector_type(8)));

#define VMCNT(n) asm volatile("s_waitcnt vmcnt(" #n ")" ::: "memory")
#define LGK0() do { asm volatile("s_waitcnt lgkmcnt(0)" ::: "memory"); __builtin_amdgcn_sched_barrier(0); } while(0)

__device__ __forceinline__ unsigned short f2bf(float f) {
  union { float f; unsigned u; } v; v.f = f;
  unsigned r = v.u + 0x7FFFu + ((v.u >> 16) & 1u);  // RNE
  return (unsigned short)(r >> 16);
}

__device__ __forceinline__ void async16(const void* g, void* l) {
  __builtin_amdgcn_global_load_lds(
      (__attribute__((address_space(1))) void*)(g),
      (__attribute__((address_space(3))) void*)(l), 16, 0, 0);
}

// ---------------- merged: router (blocks 0..1023) + convert gate_up (rest) ----------------
__global__ void gu_router_kernel(const float* __restrict__ W, unsigned short* __restrict__ W1T,
                                 const float* __restrict__ x, const float* __restrict__ rw,
                                 int* __restrict__ topk_idx, float* __restrict__ topk_w,
                                 int* __restrict__ counts) {
  int bid = blockIdx.x;
  if (bid < RT_BLOCKS) {
    int wave = threadIdx.x >> 6, lane = threadIdx.x & 63;
    int t = bid * 4 + wave;
    const float* xr = x + (size_t)t * H_DIM;
    float acc[E_NUM];
#pragma unroll
    for (int e = 0; e < E_NUM; e++) acc[e] = 0.f;
    for (int h = lane; h < H_DIM; h += 64) {
      float xv = xr[h];
      const float* wr = rw + h * E_NUM;
#pragma unroll
      for (int e = 0; e < E_NUM; e++) acc[e] += xv * wr[e];
    }
#pragma unroll
    for (int e = 0; e < E_NUM; e++) {
      float v = acc[e];
#pragma unroll
      for (int s = 32; s > 0; s >>= 1) v += __shfl_xor(v, s, 64);
      acc[e] = v;
    }
    if (lane == 0) {
      float mx = acc[0];
#pragma unroll
      for (int e = 1; e < E_NUM; e++) mx = fmaxf(mx, acc[e]);
      float p[E_NUM], s = 0.f;
#pragma unroll
      for (int e = 0; e < E_NUM; e++) { p[e] = __expf(acc[e] - mx); s += p[e]; }
      float inv = 1.0f / s;
      int i0 = 0;
#pragma unroll
      for (int e = 1; e < E_NUM; e++) if (p[e] > p[i0]) i0 = e;
      int i1 = (i0 == 0) ? 1 : 0;
#pragma unroll
      for (int e = 0; e < E_NUM; e++) if (e != i0 && p[e] > p[i1]) i1 = e;
      topk_idx[t * 2]     = i0;
      topk_idx[t * 2 + 1] = i1;
      topk_w[t * 2]       = p[i0] * inv;
      topk_w[t * 2 + 1]   = p[i1] * inv;
      atomicAdd(&counts[i0], 1);
      atomicAdd(&counts[i1], 1);
    }
    return;
  }
  int b = bid - RT_BLOCKS;
  int kt = b & 63;
  int ntb = (b >> 6) % NT1;
  int e = b / (64 * NT1);
  int c = threadIdx.x;
  int n_phys = ntb * 256 + c;
  int blk = n_phys >> 4;
  int src_col = ((blk >> 1) << 4) + (n_phys & 15) + ((blk & 1) ? I_DIM : 0);
  const float* src = W + ((size_t)e * H_DIM + (size_t)kt * 32) * (2 * I_DIM) + src_col;
  unsigned short* dst = W1T + ((size_t)e * N1DIM + n_phys) * H_DIM + kt * 32;
  float v[32];
#pragma unroll
  for (int k = 0; k < 32; k++) v[k] = src[(size_t)k * (2 * I_DIM)];
#pragma unroll
  for (int p = 0; p < 4; p++) {
    ushortx8 o;
#pragma unroll
    for (int j2 = 0; j2 < 8; j2++) o[j2] = f2bf(v[p * 8 + j2]);
    *(ushortx8*)(dst + p * 8) = o;
  }
}

// ---------------- scan: single 256-row tile table ----------------
__global__ void scan_kernel(const int* __restrict__ counts, int* __restrict__ cursors,
                            int* __restrict__ t1e, int* __restrict__ t1m0, int* __restrict__ t1end) {
  if (threadIdx.x == 0) {
    int o = 0, n1t = 0;
    for (int e = 0; e < E_NUM; e++) {
      int c = counts[e];
      cursors[e] = o;
      int n1 = (c + 255) >> 8;
      for (int j = 0; j < n1; j++) { t1e[n1t] = e; t1m0[n1t] = o + 256 * j; t1end[n1t] = o + c; n1t++; }
      o += 256 * n1;
    }
    for (; n1t < MAXMT; n1t++) t1e[n1t] = -1;
  }
}

__global__ void assign_kernel(const int* __restrict__ topk_idx, int* __restrict__ cursors,
                              int* __restrict__ row_of, int* __restrict__ tok_of) {
  int i = blockIdx.x * blockDim.x + threadIdx.x;
  int e = topk_idx[i];
  int row = atomicAdd(&cursors[e], 1);
  row_of[i] = row;
  tok_of[row] = i >> 1;
}

// ---------------- gather: x -> Xp row-major bf16, padded rows clamped ----------------
__global__ void gather_kernel(const float* __restrict__ x, const int* __restrict__ tok_of,
                              const int* __restrict__ t1e, const int* __restrict__ t1m0,
                              const int* __restrict__ t1end, unsigned short* __restrict__ Xp) {
  int mt = blockIdx.x >> 8;
  if (t1e[mt] < 0) return;
  int r = blockIdx.x & 255;
  int row = t1m0[mt] + r;
  int end = t1end[mt];
  int rr = row < end ? row : end - 1;
  int tok = tok_of[rr];
  const float4* src = (const float4*)(x + (size_t)tok * H_DIM);
  int i = threadIdx.x;
  float4 v0 = src[i * 2], v1 = src[i * 2 + 1];
  ushortx8 o;
  o[0] = f2bf(v0.x); o[1] = f2bf(v0.y); o[2] = f2bf(v0.z); o[3] = f2bf(v0.w);
  o[4] = f2bf(v1.x); o[5] = f2bf(v1.y); o[6] = f2bf(v1.z); o[7] = f2bf(v1.w);
  *(ushortx8*)(Xp + (size_t)row * H_DIM + i * 8) = o;
}

// staging macros (names resolved in kernel scope)
#define STG_A(lb) do { async16(gA0, (lb) + dA0); gA0 += 32; async16(gA1, (lb) + dA1); gA1 += 32; } while(0)
#define STG_B(lb) do { async16(gB0, (lb) + dB0); gB0 += 32; async16(gB1, (lb) + dB1); gB1 += 32; } while(0)

// ---------------- GEMM1 (+ folded convert_dn): 256x256, BK=32, ring-4, counted vmcnt ----------
__global__ __launch_bounds__(512, 2) void gemm1_kernel(
    const unsigned short* __restrict__ Xp, const unsigned short* __restrict__ W1T,
    const float* __restrict__ Wdn, unsigned short* __restrict__ WdT,
    const int* __restrict__ t1e, const int* __restrict__ t1m0, const int* __restrict__ t1end,
    unsigned short* __restrict__ Hmid) {
  extern __shared__ unsigned short sm[];
  int bid = blockIdx.x;
  int tid = threadIdx.x;
  if (bid >= G1_BLOCKS) {
    // convert down (E,I,H) f32 -> WdT[e][n=H][k=I] bf16 (fills gemm1's idle round-2 CUs)
    int db = bid - G1_BLOCKS;
    int kt = db % NKT2;
    int nb = (db / NKT2) & 3;
    int e  = db / (NKT2 * 4);
    int n  = nb * 512 + tid;
    const float* src = Wdn + (size_t)e * I_DIM * H_DIM + (size_t)kt * 32 * H_DIM + n;
    unsigned short* dst = WdT + ((size_t)e * H_DIM + n) * I_DIM + kt * 32;
    float v[32];
#pragma unroll
    for (int k = 0; k < 32; k++) v[k] = src[(size_t)k * H_DIM];
#pragma unroll
    for (int p = 0; p < 4; p++) {
      ushortx8 o;
#pragma unroll
      for (int j2 = 0; j2 < 8; j2++) o[j2] = f2bf(v[p * 8 + j2]);
      *(ushortx8*)(dst + p * 8) = o;
    }
    return;
  }
  int xcd = bid & 7, jj = bid >> 3;
  int mt = xcd * 5 + jj / NT1, nt = jj % NT1;
  int e = t1e[mt];
  if (e < 0) return;
  int m0 = t1m0[mt], rend = t1end[mt];
  int n0 = nt * 256;
  int wave = tid >> 6, lane = tid & 63;
  int wm = wave >> 2, wn = wave & 3;
  int l15 = lane & 15, qq = lane >> 4;

  // stage units: wave-contiguous, inverse-swizzled global source (rule 21)
  int u0 = wave * 128 + lane, u1 = u0 + 64;
  int r0 = u0 >> 2, s0 = (u0 & 3) ^ ((u0 >> 3) & 3);
  int r1 = u1 >> 2, s1 = (u1 & 3) ^ ((u1 >> 3) & 3);
  const unsigned short* gA0 = Xp + (size_t)(m0 + r0) * H_DIM + s0 * 8;
  const unsigned short* gA1 = Xp + (size_t)(m0 + r1) * H_DIM + s1 * 8;
  const unsigned short* gB0 = W1T + ((size_t)e * N1DIM + (n0 + r0)) * H_DIM + s0 * 8;
  const unsigned short* gB1 = W1T + ((size_t)e * N1DIM + (n0 + r1)) * H_DIM + s1 * 8;
  int dA0 = u0 * 8, dA1 = u1 * 8;
  int dB0 = 8192 + u0 * 8, dB1 = 8192 + u1 * 8;

  // swizzled ds_read bases (bytes): unit nibble = q ^ ((row>>1)&3)
  int sw = (qq ^ ((l15 >> 1) & 3)) * 16;
  int sA = (wm * 128 + l15) * 64 + sw;
  int sB = 16384 + (wn * 64 + l15) * 64 + sw;

  STG_A(sm); STG_B(sm);
  { unsigned short* lb = sm + BUF1U; STG_A(lb); STG_B(lb); }
  floatx4 acc[8][4] = {};
  VMCNT(4);
  __builtin_amdgcn_s_barrier();

  for (int t = 0; t < NKT1; t++) {
    const char* sb = (const char*)(sm + (t & 3) * BUF1U);
    unsigned short* lb = sm + ((t + 2) & 3) * BUF1U;
    bool pf = (t + 2 < NKT1);
    bf16x8 a[8], b0, b1, b2, b3;
#pragma unroll
    for (int fr = 0; fr < 8; fr++) a[fr] = *(const bf16x8*)(sb + sA + fr * 1024);
    b0 = *(const bf16x8*)(sb + sB);
    b1 = *(const bf16x8*)(sb + sB + 1024);
    if (pf) STG_A(lb);
    __builtin_amdgcn_s_barrier();
    LGK0();
    __builtin_amdgcn_s_setprio(1);
#pragma unroll
    for (int fr = 0; fr < 8; fr++) {
      acc[fr][0] = __builtin_amdgcn_mfma_f32_16x16x32_bf16(a[fr], b0, acc[fr][0], 0, 0, 0);
      acc[fr][1] = __builtin_amdgcn_mfma_f32_16x16x32_bf16(a[fr], b1, acc[fr][1], 0, 0, 0);
    }
    __builtin_amdgcn_s_setprio(0);
    __builtin_amdgcn_s_barrier();
    b2 = *(const bf16x8*)(sb + sB + 2048);
    b3 = *(const bf16x8*)(sb + sB + 3072);
    if (pf) { STG_B(lb); VMCNT(4); } else { VMCNT(0); }
    __builtin_amdgcn_s_barrier();
    LGK0();
    __builtin_amdgcn_s_setprio(1);
#pragma unroll
    for (int fr = 0; fr < 8; fr++) {
      acc[fr][2] = __builtin_amdgcn_mfma_f32_16x16x32_bf16(a[fr], b2, acc[fr][2], 0, 0, 0);
      acc[fr][3] = __builtin_amdgcn_mfma_f32_16x16x32_bf16(a[fr], b3, acc[fr][3], 0, 0, 0);
    }
    __builtin_amdgcn_s_setprio(0);
  }

  // epilogue: silu(gate)*up from (even,odd) ni pairs -> Hmid row-major [row][1408]
  int rb = wm * 128 + (lane >> 4) * 4;
  int lc0 = nt * 128 + wn * 32 + l15;
#pragma unroll
  for (int fr = 0; fr < 8; fr++) {
#pragma unroll
    for (int p = 0; p < 2; p++) {
      int lcol = lc0 + p * 16;
#pragma unroll
      for (int r = 0; r < 4; r++) {
        int arow = m0 + rb + fr * 16 + r;
        if (arow < rend) {
          float g = acc[fr][2 * p][r];
          float u = acc[fr][2 * p + 1][r];
          float s = g / (1.0f + __expf(-g));
          Hmid[(size_t)arow * I_DIM + lcol] = f2bf(s * u);
        }
      }
    }
  }
}

// ---------------- GEMM2: 256x256, BK=32, ring-4 (identical proven geometry) ----------------
__global__ __launch_bounds__(512, 2) void gemm2_kernel(
    const unsigned short* __restrict__ Hmid, const unsigned short* __restrict__ WdT,
    const int* __restrict__ t1e, const int* __restrict__ t1m0, const int* __restrict__ t1end,
    float* __restrict__ H2) {
  extern __shared__ unsigned short sm[];
  int bid = blockIdx.x;
  int xcd = bid & 7, jj = bid >> 3;
  int mt = xcd * 5 + (jj >> 3), nt = jj & 7;
  int e = t1e[mt];
  if (e < 0) return;
  int m0 = t1m0[mt], rend = t1end[mt];
  int n0 = nt * 256;
  int tid = threadIdx.x, wave = tid >> 6, lane = tid & 63;
  int wm = wave >> 2, wn = wave & 3;
  int l15 = lane & 15, qq = lane >> 4;

  int u0 = wave * 128 + lane, u1 = u0 + 64;
  int r0 = u0 >> 2, s0 = (u0 & 3) ^ ((u0 >> 3) & 3);
  int r1 = u1 >> 2, s1 = (u1 & 3) ^ ((u1 >> 3) & 3);
  const unsigned short* gA0 = Hmid + (size_t)(m0 + r0) * I_DIM + s0 * 8;
  const unsigned short* gA1 = Hmid + (size_t)(m0 + r1) * I_DIM + s1 * 8;
  const unsigned short* gB0 = WdT + ((size_t)e * H_DIM + (n0 + r0)) * I_DIM + s0 * 8;
  const unsigned short* gB1 = WdT + ((size_t)e * H_DIM + (n0 + r1)) * I_DIM + s1 * 8;
  int dA0 = u0 * 8, dA1 = u1 * 8;
  int dB0 = 8192 + u0 * 8, dB1 = 8192 + u1 * 8;

  int sw = (qq ^ ((l15 >> 1) & 3)) * 16;
  int sA = (wm * 128 + l15) * 64 + sw;
  int sB = 16384 + (wn * 64 + l15) * 64 + sw;

  STG_A(sm); STG_B(sm);
  { unsigned short* lb = sm + BUF1U; STG_A(lb); STG_B(lb); }
  floatx4 acc[8][4] = {};
  VMCNT(4);
  __builtin_amdgcn_s_barrier();

  for (int t = 0; t < NKT2; t++) {
    const char* sb = (const char*)(sm + (t & 3) * BUF1U);
    unsigned short* lb = sm + ((t + 2) & 3) * BUF1U;
    bool pf = (t + 2 < NKT2);
    bf16x8 a[8], b0, b1, b2, b3;
#pragma unroll
    for (int fr = 0; fr < 8; fr++) a[fr] = *(const bf16x8*)(sb + sA + fr * 1024);
    b0 = *(const bf16x8*)(sb + sB);
    b1 = *(const bf16x8*)(sb + sB + 1024);
    if (pf) STG_A(lb);
    __builtin_amdgcn_s_barrier();
    LGK0();
    __builtin_amdgcn_s_setprio(1);
#pragma unroll
    for (int fr = 0; fr < 8; fr++) {
      acc[fr][0] = __builtin_amdgcn_mfma_f32_16x16x32_bf16(a[fr], b0, acc[fr][0], 0, 0, 0);
      acc[fr][1] = __builtin_amdgcn_mfma_f32_16x16x32_bf16(a[fr], b1, acc[fr][1], 0, 0, 0);
    }
    __builtin_amdgcn_s_setprio(0);
    __builtin_amdgcn_s_barrier();
    b2 = *(const bf16x8*)(sb + sB + 2048);
    b3 = *(const bf16x8*)(sb + sB + 3072);
    if (pf) { STG_B(lb); VMCNT(4); } else { VMCNT(0); }
    __builtin_amdgcn_s_barrier();
    LGK0();
    __builtin_amdgcn_s_setprio(1);
#pragma unroll
    for (int fr = 0; fr < 8; fr++) {
      acc[fr][2] = __builtin_amdgcn_mfma_f32_16x16x32_bf16(a[fr], b2, acc[fr][2], 0, 0, 0);
      acc[fr][3] = __builtin_amdgcn_mfma_f32_16x16x32_bf16(a[fr], b3, acc[fr][3], 0, 0, 0);
    }
    __builtin_amdgcn_s_setprio(0);
  }

  int rb = wm * 128 + (lane >> 4) * 4;
  int cb = n0 + wn * 64 + l15;
#pragma unroll
  for (int fr = 0; fr < 8; fr++) {
#pragma unroll
    for (int ni = 0; ni < 4; ni++) {
#pragma unroll
      for (int r = 0; r < 4; r++) {
        int arow = m0 + rb + fr * 16 + r;
        if (arow < rend) H2[(size_t)arow * H_DIM + cb + ni * 16] = acc[fr][ni][r];
      }
    }
  }
}

// ---------------- combine ----------------
__global__ void combine_kernel(const float* __restrict__ H2, const int* __restrict__ row_of,
                               const float* __restrict__ topk_w, float* __restrict__ out) {
  int t = blockIdx.x >> 1;
  int part = blockIdx.x & 1;
  int c = part * 1024 + threadIdx.x * 4;
  int r0 = row_of[t * 2], r1 = row_of[t * 2 + 1];
  float w0 = topk_w[t * 2], w1 = topk_w[t * 2 + 1];
  float4 a = *(const float4*)(H2 + (size_t)r0 * H_DIM + c);
  float4 b = *(const float4*)(H2 + (size_t)r1 * H_DIM + c);
  float4 o;
  o.x = w0 * a.x + w1 * b.x;
  o.y = w0 * a.y + w1 * b.y;
  o.z = w0 * a.z + w1 * b.z;
  o.w = w0 * a.w + w1 * b.w;
  *(float4*)(out + (size_t)t * H_DIM + c) = o;
}

extern "C" void kernel_launch(void* const* d_in, const int* in_sizes, int n_in,
                              void* d_out, int out_size, void* d_ws, size_t ws_size,
                              hipStream_t stream) {
  const float* x   = (const float*)d_in[0];
  const float* rw  = (const float*)d_in[1];
  const float* wgu = (const float*)d_in[2];
  const float* wdn = (const float*)d_in[3];
  float* out = (float*)d_out;

  static bool attr_done = false;
  if (!attr_done) {
    hipFuncSetAttribute(reinterpret_cast<const void*>(gemm1_kernel),
                        hipFuncAttributeMaxDynamicSharedMemorySize, LDS1);
    hipFuncSetAttribute(reinterpret_cast<const void*>(gemm2_kernel),
                        hipFuncAttributeMaxDynamicSharedMemorySize, LDS1);
    attr_done = true;
  }

  char* ws = (char*)d_ws;
  size_t off = 0;
  auto alloc = [&](size_t b) {
    char* p = ws + off;
    off = (off + b + 255) & ~(size_t)255;
    return p;
  };
  unsigned short* W1T  = (unsigned short*)alloc((size_t)E_NUM * N1DIM * H_DIM * 2);
  unsigned short* WdT  = (unsigned short*)alloc((size_t)E_NUM * H_DIM * I_DIM * 2);
  unsigned short* Xp   = (unsigned short*)alloc((size_t)MAXROWS * H_DIM * 2);
  unsigned short* Hmid = (unsigned short*)alloc((size_t)MAXROWS * I_DIM * 2);
  float* H2            = (float*)alloc((size_t)MAXROWS * H_DIM * 4);
  int*   topk_idx      = (int*)alloc(RTOT * 4);
  float* topk_w        = (float*)alloc(RTOT * 4);
  int*   row_of        = (int*)alloc(RTOT * 4);
  int*   tok_of        = (int*)alloc((size_t)MAXROWS * 4);
  int*   counts        = (int*)alloc(256);
  int*   cursors       = (int*)alloc(256);
  int*   t1e           = (int*)alloc(MAXMT * 4);
  int*   t1m0          = (int*)alloc(MAXMT * 4);
  int*   t1end         = (int*)alloc(MAXMT * 4);

  hipMemsetAsync(counts, 0, E_NUM * sizeof(int), stream);

  gu_router_kernel<<<RT_BLOCKS + GU_BLOCKS, 256, 0, stream>>>(wgu, W1T, x, rw, topk_idx, topk_w, counts);
  scan_kernel<<<1, 64, 0, stream>>>(counts, cursors, t1e, t1m0, t1end);
  assign_kernel<<<RTOT / 256, 256, 0, stream>>>(topk_idx, cursors, row_of, tok_of);
  gather_kernel<<<MAXMT * 256, 256, 0, stream>>>(x, tok_of, t1e, t1m0, t1end, Xp);
  gemm1_kernel<<<G1_BLOCKS + DN_BLOCKS, 512, LDS1, stream>>>(Xp, W1T, wdn, WdT, t1e, t1m0, t1end, Hmid);
  gemm2_kernel<<<320, 512, LDS1, stream>>>(Hmid, WdT, t1e, t1m0, t1end, H2);
  combine_kernel<<<T_TOK * 2, 256, 0, stream>>>(H2, row_of, topk_w, out);
}

// Round 4
// 693.618 us; speedup vs baseline: 1.1149x; 1.0226x over previous
//
#include <hip/hip_runtime.h>
#include <hip/hip_bf16.h>

#define T_TOK 4096
#define H_DIM 2048
#define E_NUM 8
#define I_DIM 1408
#define RTOT  8192
#define N1DIM 2816          // gemm1 N (gate|up interleaved)
#define MAXMT 40
#define MAXROWS 10752
#define NT1   11
#define NKT1  64
#define NKT2  44
#define G1_BLOCKS 440       // 8 xcd * 5 mt * 11 nt
#define GU_TILES 11264      // 32 kt * 44 j * 8 e
#define DN_BLOCKS 2816      // 22 kt * 16 nb * 8 e  (folded into gemm1 tail)
#define RT_BLOCKS 1024

// both GEMMs: ring4 x (A 16KB + B 16KB) = 128 KB  (proven footprint)
#define BUF1U 16384         // ushorts per ring slot
#define LDS1  131072

typedef __bf16 bf16x8 __attribute__((ext_vector_type(8)));
typedef float  floatx4 __attribute__((ext_vector_type(4)));
typedef unsigned short ushortx8 __attribute__((ext_vector_type(8)));

#define VMCNT(n) asm volatile("s_waitcnt vmcnt(" #n ")" ::: "memory")
#define LGK0() do { asm volatile("s_waitcnt lgkmcnt(0)" ::: "memory"); __builtin_amdgcn_sched_barrier(0); } while(0)

__device__ __forceinline__ unsigned short f2bf(float f) {
  union { float f; unsigned u; } v; v.f = f;
  unsigned r = v.u + 0x7FFFu + ((v.u >> 16) & 1u);  // RNE
  return (unsigned short)(r >> 16);
}

__device__ __forceinline__ void async16(const void* g, void* l) {
  __builtin_amdgcn_global_load_lds(
      (__attribute__((address_space(1))) void*)(g),
      (__attribute__((address_space(3))) void*)(l), 16, 0, 0);
}

// ---------------- merged: router (blocks 0..1023) + gate_up convert via LDS transpose ----------------
// W1T[e][n_phys][k] bf16 row-major; n_phys interleaves gate/up at 16-col granularity.
__global__ void prep_kernel(const float* __restrict__ W, unsigned short* __restrict__ W1T,
                            const float* __restrict__ x, const float* __restrict__ rw,
                            int* __restrict__ topk_idx, float* __restrict__ topk_w,
                            int* __restrict__ counts) {
  __shared__ unsigned short t[64][72];   // +8 pad: 144B rows, 8B-aligned ushort4
  int bid = blockIdx.x;
  if (bid < RT_BLOCKS) {
    int wave = threadIdx.x >> 6, lane = threadIdx.x & 63;
    int tk = bid * 4 + wave;
    const float* xr = x + (size_t)tk * H_DIM;
    float acc[E_NUM];
#pragma unroll
    for (int e = 0; e < E_NUM; e++) acc[e] = 0.f;
    for (int h = lane; h < H_DIM; h += 64) {
      float xv = xr[h];
      const float* wr = rw + h * E_NUM;
#pragma unroll
      for (int e = 0; e < E_NUM; e++) acc[e] += xv * wr[e];
    }
#pragma unroll
    for (int e = 0; e < E_NUM; e++) {
      float v = acc[e];
#pragma unroll
      for (int s = 32; s > 0; s >>= 1) v += __shfl_xor(v, s, 64);
      acc[e] = v;
    }
    if (lane == 0) {
      float mx = acc[0];
#pragma unroll
      for (int e = 1; e < E_NUM; e++) mx = fmaxf(mx, acc[e]);
      float p[E_NUM], s = 0.f;
#pragma unroll
      for (int e = 0; e < E_NUM; e++) { p[e] = __expf(acc[e] - mx); s += p[e]; }
      float inv = 1.0f / s;
      int i0 = 0;
#pragma unroll
      for (int e = 1; e < E_NUM; e++) if (p[e] > p[i0]) i0 = e;
      int i1 = (i0 == 0) ? 1 : 0;
#pragma unroll
      for (int e = 0; e < E_NUM; e++) if (e != i0 && p[e] > p[i1]) i1 = e;
      topk_idx[tk * 2]     = i0;
      topk_idx[tk * 2 + 1] = i1;
      topk_w[tk * 2]       = p[i0] * inv;
      topk_w[tk * 2 + 1]   = p[i1] * inv;
      atomicAdd(&counts[i0], 1);
      atomicAdd(&counts[i1], 1);
    }
    return;
  }
  // gate_up convert: output tile j covers W1T rows [64j, 64j+64) = gate[32j..+32) ∪ up[32j..+32)
  int b = bid - RT_BLOCKS;
  int kt = b & 31;              // over H/64
  int j  = (b >> 5) % 44;      // output 64-row n_phys tile
  int e  = b / (32 * 44);
  int f4 = threadIdx.x & 15, kr = threadIdx.x >> 4;
  int up = f4 >> 3, cc = (f4 & 7) * 4;               // source col offset in [0,32)
  int src_col = (up ? I_DIM : 0) + 32 * j + cc;
  int lrow = 32 * (cc >> 4) + 16 * up + (cc & 15);   // local output row of src col cc
  const float* src = W + ((size_t)e * H_DIM + (size_t)kt * 64) * (2 * I_DIM) + src_col;
#pragma unroll
  for (int p = 0; p < 4; p++) {
    int k = kr + p * 16;
    float4 v = *(const float4*)(src + (size_t)k * (2 * I_DIM));
    t[lrow + 0][k] = f2bf(v.x);
    t[lrow + 1][k] = f2bf(v.y);
    t[lrow + 2][k] = f2bf(v.z);
    t[lrow + 3][k] = f2bf(v.w);
  }
  __syncthreads();
  int c = threadIdx.x & 15, nr = threadIdx.x >> 4;
  unsigned short* Op = W1T + ((size_t)e * N1DIM + 64 * j) * H_DIM + kt * 64;
#pragma unroll
  for (int p = 0; p < 4; p++) {
    int n = nr + p * 16;
    *(ushort4*)(Op + (size_t)n * H_DIM + c * 4) = *(const ushort4*)&t[n][c * 4];
  }
}

// ---------------- scan: single 256-row tile table ----------------
__global__ void scan_kernel(const int* __restrict__ counts, int* __restrict__ cursors,
                            int* __restrict__ t1e, int* __restrict__ t1m0, int* __restrict__ t1end) {
  if (threadIdx.x == 0) {
    int o = 0, n1t = 0;
    for (int e = 0; e < E_NUM; e++) {
      int c = counts[e];
      cursors[e] = o;
      int n1 = (c + 255) >> 8;
      for (int j = 0; j < n1; j++) { t1e[n1t] = e; t1m0[n1t] = o + 256 * j; t1end[n1t] = o + c; n1t++; }
      o += 256 * n1;
    }
    for (; n1t < MAXMT; n1t++) t1e[n1t] = -1;
  }
}

__global__ void assign_kernel(const int* __restrict__ topk_idx, int* __restrict__ cursors,
                              int* __restrict__ row_of, int* __restrict__ tok_of) {
  int i = blockIdx.x * blockDim.x + threadIdx.x;
  int e = topk_idx[i];
  int row = atomicAdd(&cursors[e], 1);
  row_of[i] = row;
  tok_of[row] = i >> 1;
}

// ---------------- gather: x -> Xp row-major bf16, padded rows clamped ----------------
__global__ void gather_kernel(const float* __restrict__ x, const int* __restrict__ tok_of,
                              const int* __restrict__ t1e, const int* __restrict__ t1m0,
                              const int* __restrict__ t1end, unsigned short* __restrict__ Xp) {
  int mt = blockIdx.x >> 8;
  if (t1e[mt] < 0) return;
  int r = blockIdx.x & 255;
  int row = t1m0[mt] + r;
  int end = t1end[mt];
  int rr = row < end ? row : end - 1;
  int tok = tok_of[rr];
  const float4* src = (const float4*)(x + (size_t)tok * H_DIM);
  int i = threadIdx.x;
  float4 v0 = src[i * 2], v1 = src[i * 2 + 1];
  ushortx8 o;
  o[0] = f2bf(v0.x); o[1] = f2bf(v0.y); o[2] = f2bf(v0.z); o[3] = f2bf(v0.w);
  o[4] = f2bf(v1.x); o[5] = f2bf(v1.y); o[6] = f2bf(v1.z); o[7] = f2bf(v1.w);
  *(ushortx8*)(Xp + (size_t)row * H_DIM + i * 8) = o;
}

// staging macros (names resolved in kernel scope)
#define STG_A(lb) do { async16(gA0, (lb) + dA0); gA0 += 32; async16(gA1, (lb) + dA1); gA1 += 32; } while(0)
#define STG_B(lb) do { async16(gB0, (lb) + dB0); gB0 += 32; async16(gB1, (lb) + dB1); gB1 += 32; } while(0)

// ---------------- GEMM1 (+ folded dn-convert w/ LDS transpose): 256x256, BK=32, ring-4 ----------
__global__ __launch_bounds__(512, 2) void gemm1_kernel(
    const unsigned short* __restrict__ Xp, const unsigned short* __restrict__ W1T,
    const float* __restrict__ Wdn, unsigned short* __restrict__ WdT,
    const int* __restrict__ t1e, const int* __restrict__ t1m0, const int* __restrict__ t1end,
    unsigned short* __restrict__ Hmid) {
  extern __shared__ unsigned short sm[];
  int bid = blockIdx.x;
  int tid = threadIdx.x;
  if (bid >= G1_BLOCKS) {
    // convert down (E,I,H) f32 -> WdT[e][n=H][k=I] bf16 via LDS transpose (128n x 64k tiles)
    int db = bid - G1_BLOCKS;
    int kt = db % 22;                 // over I/64
    int nb = (db / 22) & 15;          // over H/128
    int e  = db / (22 * 16);
    int k0 = kt * 64, n0 = nb * 128;
    unsigned short (*t2)[72] = (unsigned short (*)[72])sm;
    int f4 = tid & 31, kr = tid >> 5;
    const float* src = Wdn + (size_t)e * I_DIM * H_DIM + (size_t)k0 * H_DIM + n0 + f4 * 4;
#pragma unroll
    for (int p = 0; p < 4; p++) {
      int k = kr + p * 16;
      float4 v = *(const float4*)(src + (size_t)k * H_DIM);
      t2[f4 * 4 + 0][k] = f2bf(v.x);
      t2[f4 * 4 + 1][k] = f2bf(v.y);
      t2[f4 * 4 + 2][k] = f2bf(v.z);
      t2[f4 * 4 + 3][k] = f2bf(v.w);
    }
    __syncthreads();
    int c = tid & 15, nr = tid >> 4;
#pragma unroll
    for (int p = 0; p < 4; p++) {
      int n = nr + p * 32;
      *(ushort4*)(WdT + ((size_t)e * H_DIM + n0 + n) * I_DIM + k0 + c * 4) = *(const ushort4*)&t2[n][c * 4];
    }
    return;
  }
  int xcd = bid & 7, jj = bid >> 3;
  int mt = xcd * 5 + jj / NT1, nt = jj % NT1;
  int e = t1e[mt];
  if (e < 0) return;
  int m0 = t1m0[mt], rend = t1end[mt];
  int n0 = nt * 256;
  int wave = tid >> 6, lane = tid & 63;
  int wm = wave >> 2, wn = wave & 3;
  int l15 = lane & 15, qq = lane >> 4;

  // stage units: wave-contiguous, inverse-swizzled global source (rule 21)
  int u0 = wave * 128 + lane, u1 = u0 + 64;
  int r0 = u0 >> 2, s0 = (u0 & 3) ^ ((u0 >> 3) & 3);
  int r1 = u1 >> 2, s1 = (u1 & 3) ^ ((u1 >> 3) & 3);
  const unsigned short* gA0 = Xp + (size_t)(m0 + r0) * H_DIM + s0 * 8;
  const unsigned short* gA1 = Xp + (size_t)(m0 + r1) * H_DIM + s1 * 8;
  const unsigned short* gB0 = W1T + ((size_t)e * N1DIM + (n0 + r0)) * H_DIM + s0 * 8;
  const unsigned short* gB1 = W1T + ((size_t)e * N1DIM + (n0 + r1)) * H_DIM + s1 * 8;
  int dA0 = u0 * 8, dA1 = u1 * 8;
  int dB0 = 8192 + u0 * 8, dB1 = 8192 + u1 * 8;

  // swizzled ds_read bases (bytes): unit nibble = q ^ ((row>>1)&3)
  int sw = (qq ^ ((l15 >> 1) & 3)) * 16;
  int sA = (wm * 128 + l15) * 64 + sw;
  int sB = 16384 + (wn * 64 + l15) * 64 + sw;

  STG_A(sm); STG_B(sm);
  { unsigned short* lb = sm + BUF1U; STG_A(lb); STG_B(lb); }
  floatx4 acc[8][4] = {};
  VMCNT(4);
  __builtin_amdgcn_s_barrier();

  for (int t = 0; t < NKT1; t++) {
    const char* sb = (const char*)(sm + (t & 3) * BUF1U);
    unsigned short* lb = sm + ((t + 2) & 3) * BUF1U;
    bool pf = (t + 2 < NKT1);
    bf16x8 a[8], b0, b1, b2, b3;
#pragma unroll
    for (int fr = 0; fr < 8; fr++) a[fr] = *(const bf16x8*)(sb + sA + fr * 1024);
    b0 = *(const bf16x8*)(sb + sB);
    b1 = *(const bf16x8*)(sb + sB + 1024);
    if (pf) STG_A(lb);
    __builtin_amdgcn_s_barrier();
    LGK0();
    __builtin_amdgcn_s_setprio(1);
#pragma unroll
    for (int fr = 0; fr < 8; fr++) {
      acc[fr][0] = __builtin_amdgcn_mfma_f32_16x16x32_bf16(a[fr], b0, acc[fr][0], 0, 0, 0);
      acc[fr][1] = __builtin_amdgcn_mfma_f32_16x16x32_bf16(a[fr], b1, acc[fr][1], 0, 0, 0);
    }
    __builtin_amdgcn_s_setprio(0);
    __builtin_amdgcn_s_barrier();
    b2 = *(const bf16x8*)(sb + sB + 2048);
    b3 = *(const bf16x8*)(sb + sB + 3072);
    if (pf) { STG_B(lb); VMCNT(4); } else { VMCNT(0); }
    __builtin_amdgcn_s_barrier();
    LGK0();
    __builtin_amdgcn_s_setprio(1);
#pragma unroll
    for (int fr = 0; fr < 8; fr++) {
      acc[fr][2] = __builtin_amdgcn_mfma_f32_16x16x32_bf16(a[fr], b2, acc[fr][2], 0, 0, 0);
      acc[fr][3] = __builtin_amdgcn_mfma_f32_16x16x32_bf16(a[fr], b3, acc[fr][3], 0, 0, 0);
    }
    __builtin_amdgcn_s_setprio(0);
  }

  // epilogue: silu(gate)*up from (even,odd) ni pairs -> Hmid row-major [row][1408]
  int rb = wm * 128 + (lane >> 4) * 4;
  int lc0 = nt * 128 + wn * 32 + l15;
#pragma unroll
  for (int fr = 0; fr < 8; fr++) {
#pragma unroll
    for (int p = 0; p < 2; p++) {
      int lcol = lc0 + p * 16;
#pragma unroll
      for (int r = 0; r < 4; r++) {
        int arow = m0 + rb + fr * 16 + r;
        if (arow < rend) {
          float g = acc[fr][2 * p][r];
          float u = acc[fr][2 * p + 1][r];
          float s = g / (1.0f + __expf(-g));
          Hmid[(size_t)arow * I_DIM + lcol] = f2bf(s * u);
        }
      }
    }
  }
}

// ---------------- GEMM2: 256x256, BK=32, ring-4 (identical proven geometry) ----------------
__global__ __launch_bounds__(512, 2) void gemm2_kernel(
    const unsigned short* __restrict__ Hmid, const unsigned short* __restrict__ WdT,
    const int* __restrict__ t1e, const int* __restrict__ t1m0, const int* __restrict__ t1end,
    float* __restrict__ H2) {
  extern __shared__ unsigned short sm[];
  int bid = blockIdx.x;
  int xcd = bid & 7, jj = bid >> 3;
  int mt = xcd * 5 + (jj >> 3), nt = jj & 7;
  int e = t1e[mt];
  if (e < 0) return;
  int m0 = t1m0[mt], rend = t1end[mt];
  int n0 = nt * 256;
  int tid = threadIdx.x, wave = tid >> 6, lane = tid & 63;
  int wm = wave >> 2, wn = wave & 3;
  int l15 = lane & 15, qq = lane >> 4;

  int u0 = wave * 128 + lane, u1 = u0 + 64;
  int r0 = u0 >> 2, s0 = (u0 & 3) ^ ((u0 >> 3) & 3);
  int r1 = u1 >> 2, s1 = (u1 & 3) ^ ((u1 >> 3) & 3);
  const unsigned short* gA0 = Hmid + (size_t)(m0 + r0) * I_DIM + s0 * 8;
  const unsigned short* gA1 = Hmid + (size_t)(m0 + r1) * I_DIM + s1 * 8;
  const unsigned short* gB0 = WdT + ((size_t)e * H_DIM + (n0 + r0)) * I_DIM + s0 * 8;
  const unsigned short* gB1 = WdT + ((size_t)e * H_DIM + (n0 + r1)) * I_DIM + s1 * 8;
  int dA0 = u0 * 8, dA1 = u1 * 8;
  int dB0 = 8192 + u0 * 8, dB1 = 8192 + u1 * 8;

  int sw = (qq ^ ((l15 >> 1) & 3)) * 16;
  int sA = (wm * 128 + l15) * 64 + sw;
  int sB = 16384 + (wn * 64 + l15) * 64 + sw;

  STG_A(sm); STG_B(sm);
  { unsigned short* lb = sm + BUF1U; STG_A(lb); STG_B(lb); }
  floatx4 acc[8][4] = {};
  VMCNT(4);
  __builtin_amdgcn_s_barrier();

  for (int t = 0; t < NKT2; t++) {
    const char* sb = (const char*)(sm + (t & 3) * BUF1U);
    unsigned short* lb = sm + ((t + 2) & 3) * BUF1U;
    bool pf = (t + 2 < NKT2);
    bf16x8 a[8], b0, b1, b2, b3;
#pragma unroll
    for (int fr = 0; fr < 8; fr++) a[fr] = *(const bf16x8*)(sb + sA + fr * 1024);
    b0 = *(const bf16x8*)(sb + sB);
    b1 = *(const bf16x8*)(sb + sB + 1024);
    if (pf) STG_A(lb);
    __builtin_amdgcn_s_barrier();
    LGK0();
    __builtin_amdgcn_s_setprio(1);
#pragma unroll
    for (int fr = 0; fr < 8; fr++) {
      acc[fr][0] = __builtin_amdgcn_mfma_f32_16x16x32_bf16(a[fr], b0, acc[fr][0], 0, 0, 0);
      acc[fr][1] = __builtin_amdgcn_mfma_f32_16x16x32_bf16(a[fr], b1, acc[fr][1], 0, 0, 0);
    }
    __builtin_amdgcn_s_setprio(0);
    __builtin_amdgcn_s_barrier();
    b2 = *(const bf16x8*)(sb + sB + 2048);
    b3 = *(const bf16x8*)(sb + sB + 3072);
    if (pf) { STG_B(lb); VMCNT(4); } else { VMCNT(0); }
    __builtin_amdgcn_s_barrier();
    LGK0();
    __builtin_amdgcn_s_setprio(1);
#pragma unroll
    for (int fr = 0; fr < 8; fr++) {
      acc[fr][2] = __builtin_amdgcn_mfma_f32_16x16x32_bf16(a[fr], b2, acc[fr][2], 0, 0, 0);
      acc[fr][3] = __builtin_amdgcn_mfma_f32_16x16x32_bf16(a[fr], b3, acc[fr][3], 0, 0, 0);
    }
    __builtin_amdgcn_s_setprio(0);
  }

  int rb = wm * 128 + (lane >> 4) * 4;
  int cb = n0 + wn * 64 + l15;
#pragma unroll
  for (int fr = 0; fr < 8; fr++) {
#pragma unroll
    for (int ni = 0; ni < 4; ni++) {
#pragma unroll
      for (int r = 0; r < 4; r++) {
        int arow = m0 + rb + fr * 16 + r;
        if (arow < rend) H2[(size_t)arow * H_DIM + cb + ni * 16] = acc[fr][ni][r];
      }
    }
  }
}

// ---------------- combine ----------------
__global__ void combine_kernel(const float* __restrict__ H2, const int* __restrict__ row_of,
                               const float* __restrict__ topk_w, float* __restrict__ out) {
  int t = blockIdx.x >> 1;
  int part = blockIdx.x & 1;
  int c = part * 1024 + threadIdx.x * 4;
  int r0 = row_of[t * 2], r1 = row_of[t * 2 + 1];
  float w0 = topk_w[t * 2], w1 = topk_w[t * 2 + 1];
  float4 a = *(const float4*)(H2 + (size_t)r0 * H_DIM + c);
  float4 b = *(const float4*)(H2 + (size_t)r1 * H_DIM + c);
  float4 o;
  o.x = w0 * a.x + w1 * b.x;
  o.y = w0 * a.y + w1 * b.y;
  o.z = w0 * a.z + w1 * b.z;
  o.w = w0 * a.w + w1 * b.w;
  *(float4*)(out + (size_t)t * H_DIM + c) = o;
}

extern "C" void kernel_launch(void* const* d_in, const int* in_sizes, int n_in,
                              void* d_out, int out_size, void* d_ws, size_t ws_size,
                              hipStream_t stream) {
  const float* x   = (const float*)d_in[0];
  const float* rw  = (const float*)d_in[1];
  const float* wgu = (const float*)d_in[2];
  const float* wdn = (const float*)d_in[3];
  float* out = (float*)d_out;

  static bool attr_done = false;
  if (!attr_done) {
    hipFuncSetAttribute(reinterpret_cast<const void*>(gemm1_kernel),
                        hipFuncAttributeMaxDynamicSharedMemorySize, LDS1);
    hipFuncSetAttribute(reinterpret_cast<const void*>(gemm2_kernel),
                        hipFuncAttributeMaxDynamicSharedMemorySize, LDS1);
    attr_done = true;
  }

  char* ws = (char*)d_ws;
  size_t off = 0;
  auto alloc = [&](size_t b) {
    char* p = ws + off;
    off = (off + b + 255) & ~(size_t)255;
    return p;
  };
  unsigned short* W1T  = (unsigned short*)alloc((size_t)E_NUM * N1DIM * H_DIM * 2);
  unsigned short* WdT  = (unsigned short*)alloc((size_t)E_NUM * H_DIM * I_DIM * 2);
  unsigned short* Xp   = (unsigned short*)alloc((size_t)MAXROWS * H_DIM * 2);
  unsigned short* Hmid = (unsigned short*)alloc((size_t)MAXROWS * I_DIM * 2);
  float* H2            = (float*)alloc((size_t)MAXROWS * H_DIM * 4);
  int*   topk_idx      = (int*)alloc(RTOT * 4);
  float* topk_w        = (float*)alloc(RTOT * 4);
  int*   row_of        = (int*)alloc(RTOT * 4);
  int*   tok_of        = (int*)alloc((size_t)MAXROWS * 4);
  int*   counts        = (int*)alloc(256);
  int*   cursors       = (int*)alloc(256);
  int*   t1e           = (int*)alloc(MAXMT * 4);
  int*   t1m0          = (int*)alloc(MAXMT * 4);
  int*   t1end         = (int*)alloc(MAXMT * 4);

  hipMemsetAsync(counts, 0, E_NUM * sizeof(int), stream);

  prep_kernel<<<RT_BLOCKS + GU_TILES, 256, 0, stream>>>(wgu, W1T, x, rw, topk_idx, topk_w, counts);
  scan_kernel<<<1, 64, 0, stream>>>(counts, cursors, t1e, t1m0, t1end);
  assign_kernel<<<RTOT / 256, 256, 0, stream>>>(topk_idx, cursors, row_of, tok_of);
  gather_kernel<<<MAXMT * 256, 256, 0, stream>>>(x, tok_of, t1e, t1m0, t1end, Xp);
  gemm1_kernel<<<G1_BLOCKS + DN_BLOCKS, 512, LDS1, stream>>>(Xp, W1T, wdn, WdT, t1e, t1m0, t1end, Hmid);
  gemm2_kernel<<<320, 512, LDS1, stream>>>(Hmid, WdT, t1e, t1m0, t1end, H2);
  combine_kernel<<<T_TOK * 2, 256, 0, stream>>>(H2, row_of, topk_w, out);
}

// Round 5
// 688.525 us; speedup vs baseline: 1.1232x; 1.0074x over previous
//
#include <hip/hip_runtime.h>
#include <hip/hip_bf16.h>

#define T_TOK 4096
#define H_DIM 2048
#define E_NUM 8
#define I_DIM 1408
#define RTOT  8192
#define N1DIM 2816          // gemm1 N (gate|up interleaved)
#define MAXMT 40
#define MAXROWS 10752
#define NT1   11
#define NKT1  64
#define NKT2  44
#define G1_BLOCKS 440       // 8 xcd * 5 mt * 11 nt
#define GU_BLOCKS 2816      // 32 kt * 11 cw * 8 e
#define DN_BLOCKS 1408      // 22 kt * 8 nw * 8 e  (folded into gemm1 tail)
#define RT_BLOCKS 1024
#define BLK1 180224         // 2816*64 ushorts per kt-slab of W1T
#define BLK2 131072         // 2048*64 ushorts per kt-slab of WdT

// both GEMMs: ring4 x (A 16KB + B 16KB) = 128 KB  (proven footprint)
#define BUF1U 16384         // ushorts per ring slot
#define LDS1  131072

typedef __bf16 bf16x8 __attribute__((ext_vector_type(8)));
typedef float  floatx4 __attribute__((ext_vector_type(4)));
typedef unsigned short ushortx8 __attribute__((ext_vector_type(8)));

#define VMCNT(n) asm volatile("s_waitcnt vmcnt(" #n ")" ::: "memory")
#define LGK0() do { asm volatile("s_waitcnt lgkmcnt(0)" ::: "memory"); __builtin_amdgcn_sched_barrier(0); } while(0)

__device__ __forceinline__ unsigned short f2bf(float f) {
  union { float f; unsigned u; } v; v.f = f;
  unsigned r = v.u + 0x7FFFu + ((v.u >> 16) & 1u);  // RNE
  return (unsigned short)(r >> 16);
}

__device__ __forceinline__ void async16(const void* g, void* l) {
  __builtin_amdgcn_global_load_lds(
      (__attribute__((address_space(1))) void*)(g),
      (__attribute__((address_space(3))) void*)(l), 16, 0, 0);
}

// ---------------- merged: router (blocks 0..1023) + gate_up convert (1KB reads, blocked writes) ----
// W1T blocked layout: [e][kt=32][np=2816][64 k] bf16; np interleaves gate/up at 16-col granularity.
__global__ void prep_kernel(const float* __restrict__ W, unsigned short* __restrict__ W1T,
                            const float* __restrict__ x, const float* __restrict__ rw,
                            int* __restrict__ topk_idx, float* __restrict__ topk_w,
                            int* __restrict__ counts) {
  __shared__ unsigned short t[64][258];   // row 516B: odd word-stride -> spread banks
  int bid = blockIdx.x;
  int tid = threadIdx.x;
  if (bid < RT_BLOCKS) {
    int wave = tid >> 6, lane = tid & 63;
    int tk = bid * 4 + wave;
    const float* xr = x + (size_t)tk * H_DIM;
    float acc[E_NUM];
#pragma unroll
    for (int e = 0; e < E_NUM; e++) acc[e] = 0.f;
    for (int h = lane; h < H_DIM; h += 64) {
      float xv = xr[h];
      const float* wr = rw + h * E_NUM;
#pragma unroll
      for (int e = 0; e < E_NUM; e++) acc[e] += xv * wr[e];
    }
#pragma unroll
    for (int e = 0; e < E_NUM; e++) {
      float v = acc[e];
#pragma unroll
      for (int s = 32; s > 0; s >>= 1) v += __shfl_xor(v, s, 64);
      acc[e] = v;
    }
    if (lane == 0) {
      float mx = acc[0];
#pragma unroll
      for (int e = 1; e < E_NUM; e++) mx = fmaxf(mx, acc[e]);
      float p[E_NUM], s = 0.f;
#pragma unroll
      for (int e = 0; e < E_NUM; e++) { p[e] = __expf(acc[e] - mx); s += p[e]; }
      float inv = 1.0f / s;
      int i0 = 0;
#pragma unroll
      for (int e = 1; e < E_NUM; e++) if (p[e] > p[i0]) i0 = e;
      int i1 = (i0 == 0) ? 1 : 0;
#pragma unroll
      for (int e = 0; e < E_NUM; e++) if (e != i0 && p[e] > p[i1]) i1 = e;
      topk_idx[tk * 2]     = i0;
      topk_idx[tk * 2 + 1] = i1;
      topk_w[tk * 2]       = p[i0] * inv;
      topk_w[tk * 2 + 1]   = p[i1] * inv;
      atomicAdd(&counts[i0], 1);
      atomicAdd(&counts[i1], 1);
    }
    return;
  }
  int b = bid - RT_BLOCKS;
  int kt = b & 31;                 // over H/64
  int cw = (b >> 5) % 11;          // 256-src-col window
  int e  = b / (32 * 11);
  int k0 = kt * 64, c0 = cw * 256;
  int f = tid & 63, kw = tid >> 6;
  const float* srcb = W + ((size_t)e * H_DIM + k0) * (2 * I_DIM) + c0 + f * 4;
  float4 vv[16];
#pragma unroll
  for (int p = 0; p < 16; p++)
    vv[p] = *(const float4*)(srcb + (size_t)(p * 4 + kw) * (2 * I_DIM));
#pragma unroll
  for (int p = 0; p < 16; p++) {
    int k = p * 4 + kw;
    ushort2 lo, hi;
    lo.x = f2bf(vv[p].x); lo.y = f2bf(vv[p].y);
    hi.x = f2bf(vv[p].z); hi.y = f2bf(vv[p].w);
    *(ushort2*)&t[k][f * 4]     = lo;
    *(ushort2*)&t[k][f * 4 + 2] = hi;
  }
  __syncthreads();
  int c = tid & 15, rg = tid >> 4;
  unsigned short* Ob = W1T + ((size_t)e * 32 + kt) * BLK1;
#pragma unroll
  for (int p = 0; p < 16; p++) {
    int rr = p * 16 + rg;
    int sc = c0 + rr;
    int np = (sc < I_DIM) ? (((sc >> 4) << 5) + (sc & 15))
                          : ((((sc - I_DIM) >> 4) << 5) + 16 + ((sc - I_DIM) & 15));
    ushort4 o;
    o.x = t[c * 4 + 0][rr]; o.y = t[c * 4 + 1][rr];
    o.z = t[c * 4 + 2][rr]; o.w = t[c * 4 + 3][rr];
    *(ushort4*)(Ob + (size_t)np * 64 + c * 4) = o;
  }
}

// ---------------- scan: single 256-row tile table ----------------
__global__ void scan_kernel(const int* __restrict__ counts, int* __restrict__ cursors,
                            int* __restrict__ t1e, int* __restrict__ t1m0, int* __restrict__ t1end) {
  if (threadIdx.x == 0) {
    int o = 0, n1t = 0;
    for (int e = 0; e < E_NUM; e++) {
      int c = counts[e];
      cursors[e] = o;
      int n1 = (c + 255) >> 8;
      for (int j = 0; j < n1; j++) { t1e[n1t] = e; t1m0[n1t] = o + 256 * j; t1end[n1t] = o + c; n1t++; }
      o += 256 * n1;
    }
    for (; n1t < MAXMT; n1t++) t1e[n1t] = -1;
  }
}

__global__ void assign_kernel(const int* __restrict__ topk_idx, int* __restrict__ cursors,
                              int* __restrict__ row_of, int* __restrict__ tok_of) {
  int i = blockIdx.x * blockDim.x + threadIdx.x;
  int e = topk_idx[i];
  int row = atomicAdd(&cursors[e], 1);
  row_of[i] = row;
  tok_of[row] = i >> 1;
}

// ---------------- gather: x -> Xp row-major bf16, padded rows clamped ----------------
__global__ void gather_kernel(const float* __restrict__ x, const int* __restrict__ tok_of,
                              const int* __restrict__ t1e, const int* __restrict__ t1m0,
                              const int* __restrict__ t1end, unsigned short* __restrict__ Xp) {
  int mt = blockIdx.x >> 8;
  if (t1e[mt] < 0) return;
  int r = blockIdx.x & 255;
  int row = t1m0[mt] + r;
  int end = t1end[mt];
  int rr = row < end ? row : end - 1;
  int tok = tok_of[rr];
  const float4* src = (const float4*)(x + (size_t)tok * H_DIM);
  int i = threadIdx.x;
  float4 v0 = src[i * 2], v1 = src[i * 2 + 1];
  ushortx8 o;
  o[0] = f2bf(v0.x); o[1] = f2bf(v0.y); o[2] = f2bf(v0.z); o[3] = f2bf(v0.w);
  o[4] = f2bf(v1.x); o[5] = f2bf(v1.y); o[6] = f2bf(v1.z); o[7] = f2bf(v1.w);
  *(ushortx8*)(Xp + (size_t)row * H_DIM + i * 8) = o;
}

// staging macros (names resolved in kernel scope)
#define STG_A(lb) do { async16(gA0, (lb) + dA0); gA0 += 32; async16(gA1, (lb) + dA1); gA1 += 32; } while(0)
#define STG_B(lb, inc) do { async16(gB0, (lb) + dB0); gB0 += (inc); async16(gB1, (lb) + dB1); gB1 += (inc); } while(0)

// ---------------- GEMM1 (+ folded dn-convert): 256x256, BK=32, ring-4, counted vmcnt ----------
__global__ __launch_bounds__(512, 2) void gemm1_kernel(
    const unsigned short* __restrict__ Xp, const unsigned short* __restrict__ W1T,
    const float* __restrict__ Wdn, unsigned short* __restrict__ WdT,
    const int* __restrict__ t1e, const int* __restrict__ t1m0, const int* __restrict__ t1end,
    unsigned short* __restrict__ Hmid) {
  extern __shared__ unsigned short sm[];
  int bid = blockIdx.x;
  int tid = threadIdx.x;
  if (bid >= G1_BLOCKS) {
    // convert down (E,I,H) f32 -> WdT blocked [e][kt=22][n=2048][64] bf16
    int db = bid - G1_BLOCKS;
    int kt = db % 22;                 // over I/64
    int nw = (db / 22) & 7;           // 256-col window over H
    int e  = db / (22 * 8);
    int k0 = kt * 64, n0w = nw * 256;
    unsigned short (*t2)[258] = (unsigned short (*)[258])sm;
    int f = tid & 63, kw = tid >> 6;   // 8 waves
    const float* srcb = Wdn + (size_t)e * I_DIM * H_DIM + (size_t)k0 * H_DIM + n0w + f * 4;
    float4 vv[8];
#pragma unroll
    for (int p = 0; p < 8; p++)
      vv[p] = *(const float4*)(srcb + (size_t)(p * 8 + kw) * H_DIM);
#pragma unroll
    for (int p = 0; p < 8; p++) {
      int k = p * 8 + kw;
      ushort2 lo, hi;
      lo.x = f2bf(vv[p].x); lo.y = f2bf(vv[p].y);
      hi.x = f2bf(vv[p].z); hi.y = f2bf(vv[p].w);
      *(ushort2*)&t2[k][f * 4]     = lo;
      *(ushort2*)&t2[k][f * 4 + 2] = hi;
    }
    __syncthreads();
    int c = tid & 15, rg = tid >> 4;   // rg 0..31
    unsigned short* Ob = WdT + ((size_t)e * 22 + kt) * BLK2;
#pragma unroll
    for (int p = 0; p < 8; p++) {
      int rr = p * 32 + rg;
      int n = n0w + rr;
      ushort4 o;
      o.x = t2[c * 4 + 0][rr]; o.y = t2[c * 4 + 1][rr];
      o.z = t2[c * 4 + 2][rr]; o.w = t2[c * 4 + 3][rr];
      *(ushort4*)(Ob + (size_t)n * 64 + c * 4) = o;
    }
    return;
  }
  int xcd = bid & 7, jj = bid >> 3;
  int mt = xcd * 5 + jj / NT1, nt = jj % NT1;
  int e = t1e[mt];
  if (e < 0) return;
  int m0 = t1m0[mt], rend = t1end[mt];
  int n0 = nt * 256;
  int wave = tid >> 6, lane = tid & 63;
  int wm = wave >> 2, wn = wave & 3;
  int l15 = lane & 15, qq = lane >> 4;

  // stage units: wave-contiguous, inverse-swizzled global source (rule 21)
  int u0 = wave * 128 + lane, u1 = u0 + 64;
  int r0 = u0 >> 2, s0 = (u0 & 3) ^ ((u0 >> 3) & 3);
  int r1 = u1 >> 2, s1 = (u1 & 3) ^ ((u1 >> 3) & 3);
  const unsigned short* gA0 = Xp + (size_t)(m0 + r0) * H_DIM + s0 * 8;
  const unsigned short* gA1 = Xp + (size_t)(m0 + r1) * H_DIM + s1 * 8;
  const unsigned short* gB0 = W1T + (size_t)e * N1DIM * H_DIM + (size_t)(n0 + r0) * 64 + s0 * 8;
  const unsigned short* gB1 = W1T + (size_t)e * N1DIM * H_DIM + (size_t)(n0 + r1) * 64 + s1 * 8;
  int dA0 = u0 * 8, dA1 = u1 * 8;
  int dB0 = 8192 + u0 * 8, dB1 = 8192 + u1 * 8;

  // swizzled ds_read bases (bytes): unit nibble = q ^ ((row>>1)&3)
  int sw = (qq ^ ((l15 >> 1) & 3)) * 16;
  int sA = (wm * 128 + l15) * 64 + sw;
  int sB = 16384 + (wn * 64 + l15) * 64 + sw;

  STG_A(sm); STG_B(sm, 32);
  { unsigned short* lb = sm + BUF1U; STG_A(lb); STG_B(lb, BLK1 - 32); }
  floatx4 acc[8][4] = {};
  VMCNT(4);
  __builtin_amdgcn_s_barrier();

  for (int t = 0; t < NKT1; t++) {
    const char* sb = (const char*)(sm + (t & 3) * BUF1U);
    unsigned short* lb = sm + ((t + 2) & 3) * BUF1U;
    bool pf = (t + 2 < NKT1);
    bf16x8 a[8], b0, b1, b2, b3;
#pragma unroll
    for (int fr = 0; fr < 8; fr++) a[fr] = *(const bf16x8*)(sb + sA + fr * 1024);
    b0 = *(const bf16x8*)(sb + sB);
    b1 = *(const bf16x8*)(sb + sB + 1024);
    if (pf) STG_A(lb);
    __builtin_amdgcn_s_barrier();
    LGK0();
    __builtin_amdgcn_s_setprio(1);
#pragma unroll
    for (int fr = 0; fr < 8; fr++) {
      acc[fr][0] = __builtin_amdgcn_mfma_f32_16x16x32_bf16(a[fr], b0, acc[fr][0], 0, 0, 0);
      acc[fr][1] = __builtin_amdgcn_mfma_f32_16x16x32_bf16(a[fr], b1, acc[fr][1], 0, 0, 0);
    }
    __builtin_amdgcn_s_setprio(0);
    __builtin_amdgcn_s_barrier();
    b2 = *(const bf16x8*)(sb + sB + 2048);
    b3 = *(const bf16x8*)(sb + sB + 3072);
    if (pf) { STG_B(lb, (t & 1) ? (BLK1 - 32) : 32); VMCNT(4); } else { VMCNT(0); }
    __builtin_amdgcn_s_barrier();
    LGK0();
    __builtin_amdgcn_s_setprio(1);
#pragma unroll
    for (int fr = 0; fr < 8; fr++) {
      acc[fr][2] = __builtin_amdgcn_mfma_f32_16x16x32_bf16(a[fr], b2, acc[fr][2], 0, 0, 0);
      acc[fr][3] = __builtin_amdgcn_mfma_f32_16x16x32_bf16(a[fr], b3, acc[fr][3], 0, 0, 0);
    }
    __builtin_amdgcn_s_setprio(0);
  }

  // epilogue: silu(gate)*up from (even,odd) ni pairs -> Hmid row-major [row][1408]
  int rb = wm * 128 + (lane >> 4) * 4;
  int lc0 = nt * 128 + wn * 32 + l15;
#pragma unroll
  for (int fr = 0; fr < 8; fr++) {
#pragma unroll
    for (int p = 0; p < 2; p++) {
      int lcol = lc0 + p * 16;
#pragma unroll
      for (int r = 0; r < 4; r++) {
        int arow = m0 + rb + fr * 16 + r;
        if (arow < rend) {
          float g = acc[fr][2 * p][r];
          float u = acc[fr][2 * p + 1][r];
          float s = g / (1.0f + __expf(-g));
          Hmid[(size_t)arow * I_DIM + lcol] = f2bf(s * u);
        }
      }
    }
  }
}

// ---------------- GEMM2: 256x256, BK=32, ring-4 (proven geometry, blocked B) ----------------
__global__ __launch_bounds__(512, 2) void gemm2_kernel(
    const unsigned short* __restrict__ Hmid, const unsigned short* __restrict__ WdT,
    const int* __restrict__ t1e, const int* __restrict__ t1m0, const int* __restrict__ t1end,
    float* __restrict__ H2) {
  extern __shared__ unsigned short sm[];
  int bid = blockIdx.x;
  int xcd = bid & 7, jj = bid >> 3;
  int mt = xcd * 5 + (jj >> 3), nt = jj & 7;
  int e = t1e[mt];
  if (e < 0) return;
  int m0 = t1m0[mt], rend = t1end[mt];
  int n0 = nt * 256;
  int tid = threadIdx.x, wave = tid >> 6, lane = tid & 63;
  int wm = wave >> 2, wn = wave & 3;
  int l15 = lane & 15, qq = lane >> 4;

  int u0 = wave * 128 + lane, u1 = u0 + 64;
  int r0 = u0 >> 2, s0 = (u0 & 3) ^ ((u0 >> 3) & 3);
  int r1 = u1 >> 2, s1 = (u1 & 3) ^ ((u1 >> 3) & 3);
  const unsigned short* gA0 = Hmid + (size_t)(m0 + r0) * I_DIM + s0 * 8;
  const unsigned short* gA1 = Hmid + (size_t)(m0 + r1) * I_DIM + s1 * 8;
  const unsigned short* gB0 = WdT + (size_t)e * H_DIM * I_DIM + (size_t)(n0 + r0) * 64 + s0 * 8;
  const unsigned short* gB1 = WdT + (size_t)e * H_DIM * I_DIM + (size_t)(n0 + r1) * 64 + s1 * 8;
  int dA0 = u0 * 8, dA1 = u1 * 8;
  int dB0 = 8192 + u0 * 8, dB1 = 8192 + u1 * 8;

  int sw = (qq ^ ((l15 >> 1) & 3)) * 16;
  int sA = (wm * 128 + l15) * 64 + sw;
  int sB = 16384 + (wn * 64 + l15) * 64 + sw;

  STG_A(sm); STG_B(sm, 32);
  { unsigned short* lb = sm + BUF1U; STG_A(lb); STG_B(lb, BLK2 - 32); }
  floatx4 acc[8][4] = {};
  VMCNT(4);
  __builtin_amdgcn_s_barrier();

  for (int t = 0; t < NKT2; t++) {
    const char* sb = (const char*)(sm + (t & 3) * BUF1U);
    unsigned short* lb = sm + ((t + 2) & 3) * BUF1U;
    bool pf = (t + 2 < NKT2);
    bf16x8 a[8], b0, b1, b2, b3;
#pragma unroll
    for (int fr = 0; fr < 8; fr++) a[fr] = *(const bf16x8*)(sb + sA + fr * 1024);
    b0 = *(const bf16x8*)(sb + sB);
    b1 = *(const bf16x8*)(sb + sB + 1024);
    if (pf) STG_A(lb);
    __builtin_amdgcn_s_barrier();
    LGK0();
    __builtin_amdgcn_s_setprio(1);
#pragma unroll
    for (int fr = 0; fr < 8; fr++) {
      acc[fr][0] = __builtin_amdgcn_mfma_f32_16x16x32_bf16(a[fr], b0, acc[fr][0], 0, 0, 0);
      acc[fr][1] = __builtin_amdgcn_mfma_f32_16x16x32_bf16(a[fr], b1, acc[fr][1], 0, 0, 0);
    }
    __builtin_amdgcn_s_setprio(0);
    __builtin_amdgcn_s_barrier();
    b2 = *(const bf16x8*)(sb + sB + 2048);
    b3 = *(const bf16x8*)(sb + sB + 3072);
    if (pf) { STG_B(lb, (t & 1) ? (BLK2 - 32) : 32); VMCNT(4); } else { VMCNT(0); }
    __builtin_amdgcn_s_barrier();
    LGK0();
    __builtin_amdgcn_s_setprio(1);
#pragma unroll
    for (int fr = 0; fr < 8; fr++) {
      acc[fr][2] = __builtin_amdgcn_mfma_f32_16x16x32_bf16(a[fr], b2, acc[fr][2], 0, 0, 0);
      acc[fr][3] = __builtin_amdgcn_mfma_f32_16x16x32_bf16(a[fr], b3, acc[fr][3], 0, 0, 0);
    }
    __builtin_amdgcn_s_setprio(0);
  }

  int rb = wm * 128 + (lane >> 4) * 4;
  int cb = n0 + wn * 64 + l15;
#pragma unroll
  for (int fr = 0; fr < 8; fr++) {
#pragma unroll
    for (int ni = 0; ni < 4; ni++) {
#pragma unroll
      for (int r = 0; r < 4; r++) {
        int arow = m0 + rb + fr * 16 + r;
        if (arow < rend) H2[(size_t)arow * H_DIM + cb + ni * 16] = acc[fr][ni][r];
      }
    }
  }
}

// ---------------- combine ----------------
__global__ void combine_kernel(const float* __restrict__ H2, const int* __restrict__ row_of,
                               const float* __restrict__ topk_w, float* __restrict__ out) {
  int t = blockIdx.x >> 1;
  int part = blockIdx.x & 1;
  int c = part * 1024 + threadIdx.x * 4;
  int r0 = row_of[t * 2], r1 = row_of[t * 2 + 1];
  float w0 = topk_w[t * 2], w1 = topk_w[t * 2 + 1];
  float4 a = *(const float4*)(H2 + (size_t)r0 * H_DIM + c);
  float4 b = *(const float4*)(H2 + (size_t)r1 * H_DIM + c);
  float4 o;
  o.x = w0 * a.x + w1 * b.x;
  o.y = w0 * a.y + w1 * b.y;
  o.z = w0 * a.z + w1 * b.z;
  o.w = w0 * a.w + w1 * b.w;
  *(float4*)(out + (size_t)t * H_DIM + c) = o;
}

extern "C" void kernel_launch(void* const* d_in, const int* in_sizes, int n_in,
                              void* d_out, int out_size, void* d_ws, size_t ws_size,
                              hipStream_t stream) {
  const float* x   = (const float*)d_in[0];
  const float* rw  = (const float*)d_in[1];
  const float* wgu = (const float*)d_in[2];
  const float* wdn = (const float*)d_in[3];
  float* out = (float*)d_out;

  static bool attr_done = false;
  if (!attr_done) {
    hipFuncSetAttribute(reinterpret_cast<const void*>(gemm1_kernel),
                        hipFuncAttributeMaxDynamicSharedMemorySize, LDS1);
    hipFuncSetAttribute(reinterpret_cast<const void*>(gemm2_kernel),
                        hipFuncAttributeMaxDynamicSharedMemorySize, LDS1);
    attr_done = true;
  }

  char* ws = (char*)d_ws;
  size_t off = 0;
  auto alloc = [&](size_t b) {
    char* p = ws + off;
    off = (off + b + 255) & ~(size_t)255;
    return p;
  };
  unsigned short* W1T  = (unsigned short*)alloc((size_t)E_NUM * N1DIM * H_DIM * 2);
  unsigned short* WdT  = (unsigned short*)alloc((size_t)E_NUM * H_DIM * I_DIM * 2);
  unsigned short* Xp   = (unsigned short*)alloc((size_t)MAXROWS * H_DIM * 2);
  unsigned short* Hmid = (unsigned short*)alloc((size_t)MAXROWS * I_DIM * 2);
  float* H2            = (float*)alloc((size_t)MAXROWS * H_DIM * 4);
  int*   topk_idx      = (int*)alloc(RTOT * 4);
  float* topk_w        = (float*)alloc(RTOT * 4);
  int*   row_of        = (int*)alloc(RTOT * 4);
  int*   tok_of        = (int*)alloc((size_t)MAXROWS * 4);
  int*   counts        = (int*)alloc(256);
  int*   cursors       = (int*)alloc(256);
  int*   t1e           = (int*)alloc(MAXMT * 4);
  int*   t1m0          = (int*)alloc(MAXMT * 4);
  int*   t1end         = (int*)alloc(MAXMT * 4);

  hipMemsetAsync(counts, 0, E_NUM * sizeof(int), stream);

  prep_kernel<<<RT_BLOCKS + GU_BLOCKS, 256, 0, stream>>>(wgu, W1T, x, rw, topk_idx, topk_w, counts);
  scan_kernel<<<1, 64, 0, stream>>>(counts, cursors, t1e, t1m0, t1end);
  assign_kernel<<<RTOT / 256, 256, 0, stream>>>(topk_idx, cursors, row_of, tok_of);
  gather_kernel<<<MAXMT * 256, 256, 0, stream>>>(x, tok_of, t1e, t1m0, t1end, Xp);
  gemm1_kernel<<<G1_BLOCKS + DN_BLOCKS, 512, LDS1, stream>>>(Xp, W1T, wdn, WdT, t1e, t1m0, t1end, Hmid);
  gemm2_kernel<<<320, 512, LDS1, stream>>>(Hmid, WdT, t1e, t1m0, t1end, H2);
  combine_kernel<<<T_TOK * 2, 256, 0, stream>>>(H2, row_of, topk_w, out);
}